// Round 4
// baseline (1607.715 us; speedup 1.0000x reference)
//
#include <hip/hip_runtime.h>

// WaveNet forward, suffix-window formulation, persistent cooperative chain.
#define BATCH   16
#define CLASSES 256
#define TLEN    4096
#define RC      32
#define SKIPC   256
#define ENDC    256
#define NLAYERS 30
#define OUT_T   32
#define NCOL    512          // b*32+tt columns
#define GBLK    16           // blocks per batch-group
#define NBLK    256          // total blocks

// ---------------------------------------------------------------- causal conv
// h0[b][c][t] = causal_b[c] + sum_cc causal_w[c][cc]*x[b][cc][t], t in [995,4095]
__global__ __launch_bounds__(256) void causal_kernel(
    const float* __restrict__ x, const float* __restrict__ w,
    const float* __restrict__ bias, float* __restrict__ h0)
{
    const int NT = 97;
    int b    = blockIdx.x / NT;
    int tile = blockIdx.x % NT;
    int t0   = 995 + tile * 32;

    __shared__ float xs[CLASSES][32];
    __shared__ float wsm[CLASSES][33];

    for (int idx = threadIdx.x; idx < CLASSES * 32; idx += 256) {
        int cc = idx >> 5, j = idx & 31;
        int t = t0 + j;
        xs[cc][j] = (t < TLEN) ? x[((size_t)b * CLASSES + cc) * TLEN + t] : 0.0f;
    }
    for (int idx = threadIdx.x; idx < RC * CLASSES; idx += 256) {
        int c = idx >> 8, cc = idx & 255;
        wsm[cc][c] = w[idx];
    }
    __syncthreads();

    int c  = threadIdx.x & 31;
    int jb = threadIdx.x >> 5;
    float acc0 = 0.f, acc1 = 0.f, acc2 = 0.f, acc3 = 0.f;
    for (int cc = 0; cc < CLASSES; ++cc) {
        float wv = wsm[cc][c];
        const float4* xr = (const float4*)&xs[cc][0];
        float4 xv = xr[jb];
        acc0 += wv * xv.x; acc1 += wv * xv.y;
        acc2 += wv * xv.z; acc3 += wv * xv.w;
    }
    float bb = bias[c];
    float accs[4] = {acc0, acc1, acc2, acc3};
    #pragma unroll
    for (int k = 0; k < 4; ++k) {
        int t = t0 + jb * 4 + k;
        if (t < TLEN) h0[((size_t)b * RC + c) * TLEN + t] = accs[k] + bb;
    }
}

// ---------------------------------------------------------------- group barrier
// Fresh counter per sync point (memset to 0 before launch). Device-scope
// release/acquire handles cross-XCD L2 non-coherence.
__device__ __forceinline__ void grp_barrier(unsigned* ctr)
{
    __syncthreads();
    if (threadIdx.x == 0) {
        __threadfence();   // release our global writes (agent scope)
        __hip_atomic_fetch_add(ctr, 1u, __ATOMIC_ACQ_REL, __HIP_MEMORY_SCOPE_AGENT);
        while (__hip_atomic_load(ctr, __ATOMIC_ACQUIRE, __HIP_MEMORY_SCOPE_AGENT) < GBLK) {
            __builtin_amdgcn_s_sleep(1);
        }
        __threadfence();
    }
    __syncthreads();
}

// ---------------------------------------------------------------- chain kernel
__global__ void __launch_bounds__(256) chain_kernel(
    float* __restrict__ hA, float* __restrict__ hB,
    float* __restrict__ zb, float* __restrict__ skipv, float* __restrict__ e1v,
    unsigned* __restrict__ bar,
    const float* __restrict__ filt_w, const float* __restrict__ filt_b,
    const float* __restrict__ gate_w, const float* __restrict__ gate_b,
    const float* __restrict__ res_w,  const float* __restrict__ res_b,
    const float* __restrict__ skip_w, const float* __restrict__ skip_b,
    const float* __restrict__ e1w, const float* __restrict__ e1b,
    const float* __restrict__ e2w, const float* __restrict__ e2b,
    float* __restrict__ out)
{
    const int tid = threadIdx.x;
    const int grp = blockIdx.x >> 4;   // batch index
    const int g   = blockIdx.x & 15;   // block within group
    const int b   = grp;

    union __align__(16) Sh {
        struct {
            float hc[RC][68], hp[RC][68], zt[RC][68];
            float wf0[RC][33], wf1[RC][33], wg0[RC][33], wg1[RC][33], wrs[RC][33];
            float bfs[RC], bgs[RC], brs[RC];
        } L;                                        // 47.6 KB
        struct { float z[320][32]; float w[10][16][32]; } E1;   // 60.1 KB
        struct { float v[256][32]; float w[16][256]; } E2;      // 48 KB
    };
    __shared__ Sh sh;

    // ---------------- 30-layer chain ----------------
    int S = 3069;
    for (int i = 0; i < NLAYERS; ++i) {
        int d = 1 << (i % 10);
        S -= d;
        int A1 = 4064 - S;
        int nT = (4096 - A1 + 63) >> 6;
        const float* hin = (i & 1) ? hB : hA;
        float*       hout = (i & 1) ? hA : hB;

        if (g < nT) {
            // stage weights (block-local)
            const float* fw = filt_w + (size_t)i * RC * RC * 2;
            const float* gw = gate_w + (size_t)i * RC * RC * 2;
            const float* rw = res_w  + (size_t)i * RC * RC;
            for (int idx = tid; idx < RC * RC; idx += 256) {
                int c = idx >> 5, c2 = idx & 31;
                sh.L.wf0[c][c2] = fw[idx * 2];  sh.L.wf1[c][c2] = fw[idx * 2 + 1];
                sh.L.wg0[c][c2] = gw[idx * 2];  sh.L.wg1[c][c2] = gw[idx * 2 + 1];
                sh.L.wrs[c][c2] = rw[idx];
            }
            if (tid < RC) {
                sh.L.bfs[tid] = filt_b[i * RC + tid];
                sh.L.bgs[tid] = gate_b[i * RC + tid];
                sh.L.brs[tid] = res_b[i * RC + tid];
            }

            for (int tile = g; tile < nT; tile += GBLK) {
                int t_lo = 4032 - (tile << 6);
                __syncthreads();
                for (int idx = tid; idx < RC * 64; idx += 256) {
                    int c2 = idx >> 6, tx = idx & 63;
                    const float* row = hin + ((size_t)b * RC + c2) * TLEN;
                    int t = t_lo + tx;
                    sh.L.hc[c2][tx] = row[t];
                    sh.L.hp[c2][tx] = row[t - d];
                }
                __syncthreads();

                int c  = tid & 31;
                int tl = tid >> 5;
                float fa[8], ga[8];
                float bfv = sh.L.bfs[c], bgv = sh.L.bgs[c];
                #pragma unroll
                for (int k = 0; k < 8; ++k) { fa[k] = bfv; ga[k] = bgv; }

                #pragma unroll 4
                for (int c2 = 0; c2 < RC; ++c2) {
                    float w0f = sh.L.wf0[c][c2], w1f = sh.L.wf1[c][c2];
                    float w0g = sh.L.wg0[c][c2], w1g = sh.L.wg1[c][c2];
                    const float4* hcr = (const float4*)&sh.L.hc[c2][0];
                    const float4* hpr = (const float4*)&sh.L.hp[c2][0];
                    float4 c0 = hcr[tl * 2], c1 = hcr[tl * 2 + 1];
                    float4 p0 = hpr[tl * 2], p1 = hpr[tl * 2 + 1];
                    float hcv[8] = {c0.x, c0.y, c0.z, c0.w, c1.x, c1.y, c1.z, c1.w};
                    float hpv[8] = {p0.x, p0.y, p0.z, p0.w, p1.x, p1.y, p1.z, p1.w};
                    #pragma unroll
                    for (int k = 0; k < 8; ++k) {
                        fa[k] += w0f * hpv[k] + w1f * hcv[k];
                        ga[k] += w0g * hpv[k] + w1g * hcv[k];
                    }
                }
                #pragma unroll
                for (int k = 0; k < 8; ++k) {
                    float e2 = __expf(2.0f * fa[k]);
                    float th = 1.0f - 2.0f / (e2 + 1.0f);
                    float sg = 1.0f / (1.0f + __expf(-ga[k]));
                    sh.L.zt[c][tl * 8 + k] = th * sg;
                }
                __syncthreads();

                float ra[8];
                float brv = sh.L.brs[c];
                #pragma unroll
                for (int k = 0; k < 8; ++k) ra[k] = brv;
                #pragma unroll 4
                for (int c2 = 0; c2 < RC; ++c2) {
                    float wv = sh.L.wrs[c][c2];
                    const float4* zr = (const float4*)&sh.L.zt[c2][0];
                    float4 z0 = zr[tl * 2], z1 = zr[tl * 2 + 1];
                    float zv[8] = {z0.x, z0.y, z0.z, z0.w, z1.x, z1.y, z1.z, z1.w};
                    #pragma unroll
                    for (int k = 0; k < 8; ++k) ra[k] += wv * zv[k];
                }
                #pragma unroll
                for (int k = 0; k < 8; ++k) {
                    int tx = tl * 8 + k;
                    sh.L.hp[c][tx] = sh.L.hc[c][tx] + ra[k];
                }
                __syncthreads();

                for (int idx = tid; idx < RC * 64; idx += 256) {
                    int c2 = idx >> 6, tx = idx & 63;
                    int t = t_lo + tx;
                    if (t >= A1) hout[((size_t)b * RC + c2) * TLEN + t] = sh.L.hp[c2][tx];
                }
                if (tile == 0) {   // z tail, K-major: zb[layer*32+c][n], n = b*32+tt
                    for (int idx = tid; idx < RC * OUT_T; idx += 256) {
                        int c2 = idx >> 5, tt = idx & 31;
                        zb[((size_t)i * RC + c2) * NCOL + b * OUT_T + tt] =
                            sh.L.zt[c2][32 + tt];
                    }
                }
            }
        }
        grp_barrier(bar + i * GBLK + grp);
    }

    // ---------------- end stage, group-local (columns b*32..b*32+31) ----------
    const int n   = tid & 31;
    const int s8  = tid >> 5;          // 0..7
    const int sc0 = g * 16;            // this block's 16 output rows

    // G1: skip[sc][n] = relu( sum_{l,k} skip_w[l][sc][k] * z[l*32+k][n] + sum_l skip_b[l][sc] )
    {
        float a0 = 0.f, a1 = 0.f;
        const float4* zb4 = (const float4*)zb;
        const float4* sw4 = (const float4*)skip_w;
        for (int ch = 0; ch < 3; ++ch) {           // 10 layers per chunk
            __syncthreads();
            for (int idx = tid; idx < 320 * 8; idx += 256) {
                int kk = idx >> 3, k4 = idx & 7;
                ((float4*)&sh.E1.z[kk][0])[k4] = zb4[(size_t)(ch * 320 + kk) * 128 + b * 8 + k4];
            }
            for (int idx = tid; idx < 10 * 16 * 8; idx += 256) {
                int l = idx >> 7, rem = idx & 127, r = rem >> 3, k4 = rem & 7;
                ((float4*)&sh.E1.w[l][r][0])[k4] =
                    sw4[((size_t)(ch * 10 + l) * SKIPC + sc0 + r) * 8 + k4];
            }
            __syncthreads();
            #pragma unroll
            for (int l = 0; l < 10; ++l) {
                #pragma unroll
                for (int k = 0; k < 32; ++k) {
                    float zv = sh.E1.z[l * 32 + k][n];
                    a0 += sh.E1.w[l][s8][k]     * zv;
                    a1 += sh.E1.w[l][s8 + 8][k] * zv;
                }
            }
        }
        float sb0 = 0.f, sb1 = 0.f;
        for (int l = 0; l < NLAYERS; ++l) {
            sb0 += skip_b[l * SKIPC + sc0 + s8];
            sb1 += skip_b[l * SKIPC + sc0 + s8 + 8];
        }
        skipv[((size_t)b * SKIPC + sc0 + s8) * 32 + n]     = fmaxf(a0 + sb0, 0.f);
        skipv[((size_t)b * SKIPC + sc0 + s8 + 8) * 32 + n] = fmaxf(a1 + sb1, 0.f);
    }
    grp_barrier(bar + NLAYERS * GBLK + grp);

    // G2: e1 = relu(e1w @ skipv + e1b)
    {
        for (int idx = tid; idx < 256 * 8; idx += 256) {
            int r = idx >> 3, k4 = idx & 7;
            ((float4*)&sh.E2.v[r][0])[k4] =
                ((const float4*)skipv)[((size_t)b * SKIPC + r) * 8 + k4];
        }
        for (int idx = tid; idx < 16 * 64; idx += 256) {
            int r = idx >> 6, k4 = idx & 63;
            ((float4*)&sh.E2.w[r][0])[k4] = ((const float4*)e1w)[(size_t)(sc0 + r) * 64 + k4];
        }
        __syncthreads();
        float a0 = e1b[sc0 + s8], a1 = e1b[sc0 + s8 + 8];
        #pragma unroll 8
        for (int k4 = 0; k4 < 64; ++k4) {
            float4 w0 = ((const float4*)&sh.E2.w[s8][0])[k4];
            float4 w1 = ((const float4*)&sh.E2.w[s8 + 8][0])[k4];
            float v0 = sh.E2.v[k4 * 4 + 0][n], v1 = sh.E2.v[k4 * 4 + 1][n];
            float v2 = sh.E2.v[k4 * 4 + 2][n], v3 = sh.E2.v[k4 * 4 + 3][n];
            a0 += w0.x * v0 + w0.y * v1 + w0.z * v2 + w0.w * v3;
            a1 += w1.x * v0 + w1.y * v1 + w1.z * v2 + w1.w * v3;
        }
        e1v[((size_t)b * ENDC + sc0 + s8) * 32 + n]     = fmaxf(a0, 0.f);
        e1v[((size_t)b * ENDC + sc0 + s8 + 8) * 32 + n] = fmaxf(a1, 0.f);
    }
    grp_barrier(bar + (NLAYERS + 1) * GBLK + grp);

    // G3: out[n_glob][sc] = e2w @ e1v + e2b
    {
        for (int idx = tid; idx < 256 * 8; idx += 256) {
            int r = idx >> 3, k4 = idx & 7;
            ((float4*)&sh.E2.v[r][0])[k4] =
                ((const float4*)e1v)[((size_t)b * ENDC + r) * 8 + k4];
        }
        for (int idx = tid; idx < 16 * 64; idx += 256) {
            int r = idx >> 6, k4 = idx & 63;
            ((float4*)&sh.E2.w[r][0])[k4] = ((const float4*)e2w)[(size_t)(sc0 + r) * 64 + k4];
        }
        __syncthreads();
        float a0 = e2b[sc0 + s8], a1 = e2b[sc0 + s8 + 8];
        #pragma unroll 8
        for (int k4 = 0; k4 < 64; ++k4) {
            float4 w0 = ((const float4*)&sh.E2.w[s8][0])[k4];
            float4 w1 = ((const float4*)&sh.E2.w[s8 + 8][0])[k4];
            float v0 = sh.E2.v[k4 * 4 + 0][n], v1 = sh.E2.v[k4 * 4 + 1][n];
            float v2 = sh.E2.v[k4 * 4 + 2][n], v3 = sh.E2.v[k4 * 4 + 3][n];
            a0 += w0.x * v0 + w0.y * v1 + w0.z * v2 + w0.w * v3;
            a1 += w1.x * v0 + w1.y * v1 + w1.z * v2 + w1.w * v3;
        }
        out[(size_t)(b * OUT_T + n) * CLASSES + sc0 + s8]     = a0;
        out[(size_t)(b * OUT_T + n) * CLASSES + sc0 + s8 + 8] = a1;
    }
}

// ---------------------------------------------------------------- launch
extern "C" void kernel_launch(void* const* d_in, const int* in_sizes, int n_in,
                              void* d_out, int out_size, void* d_ws, size_t ws_size,
                              hipStream_t stream)
{
    const float* x        = (const float*)d_in[0];
    const float* causal_w = (const float*)d_in[1];
    const float* causal_b = (const float*)d_in[2];
    const float* filt_w   = (const float*)d_in[3];
    const float* filt_b   = (const float*)d_in[4];
    const float* gate_w   = (const float*)d_in[5];
    const float* gate_b   = (const float*)d_in[6];
    const float* res_w    = (const float*)d_in[7];
    const float* res_b    = (const float*)d_in[8];
    const float* skip_w   = (const float*)d_in[9];
    const float* skip_b   = (const float*)d_in[10];
    const float* e1w      = (const float*)d_in[11];
    const float* e1b      = (const float*)d_in[12];
    const float* e2w      = (const float*)d_in[13];
    const float* e2b      = (const float*)d_in[14];
    float* outp           = (float*)d_out;

    const size_t HSZ = (size_t)BATCH * RC * TLEN;      // 2,097,152 floats
    float* hA    = (float*)d_ws;
    float* hB    = hA + HSZ;
    float* zb    = hB + HSZ;                           // 960 * 512
    float* skipv = zb + (size_t)NLAYERS * RC * NCOL;   // 256*512 (b-major, 32-col slices)
    float* e1v   = skipv + (size_t)SKIPC * NCOL;
    unsigned* bar = (unsigned*)(e1v + (size_t)ENDC * NCOL);  // 32*16 counters

    hipMemsetAsync(bar, 0, (NLAYERS + 2) * GBLK * sizeof(unsigned), stream);

    causal_kernel<<<dim3(BATCH * 97), dim3(256), 0, stream>>>(x, causal_w, causal_b, hA);

    void* args[] = {
        (void*)&hA, (void*)&hB, (void*)&zb, (void*)&skipv, (void*)&e1v, (void*)&bar,
        (void*)&filt_w, (void*)&filt_b, (void*)&gate_w, (void*)&gate_b,
        (void*)&res_w, (void*)&res_b, (void*)&skip_w, (void*)&skip_b,
        (void*)&e1w, (void*)&e1b, (void*)&e2w, (void*)&e2b, (void*)&outp
    };
    hipLaunchCooperativeKernel((const void*)chain_kernel, dim3(NBLK), dim3(256),
                               args, 0, stream);
}

// Round 6
// 1524.500 us; speedup vs baseline: 1.0546x; 1.0546x over previous
//
#include <hip/hip_runtime.h>

// WaveNet forward, suffix-window formulation, persistent cooperative chain.
// R6: wave-parallel padded group barrier (no leader, no RMW), NB=32 w/ fallback.
#define BATCH   16
#define CLASSES 256
#define TLEN    4096
#define RC      32
#define SKIPC   256
#define ENDC    256
#define NLAYERS 30
#define OUT_T   32
#define NCOL    512          // b*32+tt columns
#define MAXNB   32           // max blocks per batch-group

// ---------------------------------------------------------------- causal conv
// h0[b][c][t] = causal_b[c] + sum_cc causal_w[c][cc]*x[b][cc][t], t in [995,4095]
__global__ __launch_bounds__(256) void causal_kernel(
    const float* __restrict__ x, const float* __restrict__ w,
    const float* __restrict__ bias, float* __restrict__ h0)
{
    const int NT = 97;
    int b    = blockIdx.x / NT;
    int tile = blockIdx.x % NT;
    int t0   = 995 + tile * 32;

    __shared__ float xs[CLASSES][32];
    __shared__ float wsm[CLASSES][33];

    for (int idx = threadIdx.x; idx < CLASSES * 32; idx += 256) {
        int cc = idx >> 5, j = idx & 31;
        int t = t0 + j;
        xs[cc][j] = (t < TLEN) ? x[((size_t)b * CLASSES + cc) * TLEN + t] : 0.0f;
    }
    for (int idx = threadIdx.x; idx < RC * CLASSES; idx += 256) {
        int c = idx >> 8, cc = idx & 255;
        wsm[cc][c] = w[idx];
    }
    __syncthreads();

    int c  = threadIdx.x & 31;
    int jb = threadIdx.x >> 5;
    float acc0 = 0.f, acc1 = 0.f, acc2 = 0.f, acc3 = 0.f;
    for (int cc = 0; cc < CLASSES; ++cc) {
        float wv = wsm[cc][c];
        const float4* xr = (const float4*)&xs[cc][0];
        float4 xv = xr[jb];
        acc0 += wv * xv.x; acc1 += wv * xv.y;
        acc2 += wv * xv.z; acc3 += wv * xv.w;
    }
    float bb = bias[c];
    float accs[4] = {acc0, acc1, acc2, acc3};
    #pragma unroll
    for (int k = 0; k < 4; ++k) {
        int t = t0 + jb * 4 + k;
        if (t < TLEN) h0[((size_t)b * RC + c) * TLEN + t] = accs[k] + bb;
    }
}

// ---------------------------------------------------------------- group barrier
// RMW-free, leaderless. Block g release-stores arr[g*32]=p (flags padded to
// 128B), then wave 0's lane j (j<nb) acquire-spins on arr[j*32] >= p. Phase p
// is monotonic so flags never need resetting. Every block scans all flags in
// parallel (one load per lane), so barrier latency is ~one L2 round trip after
// the last arrival, with no leader->follower extra hop.
__device__ __forceinline__ void grp_barrier(volatile unsigned* arr,
                                            int g, int nb, unsigned p)
{
    __syncthreads();
    if (threadIdx.x == 0) {
        __hip_atomic_store((unsigned*)(arr + (size_t)g * 32), p,
                           __ATOMIC_RELEASE, __HIP_MEMORY_SCOPE_AGENT);
    }
    if (threadIdx.x < 64) {
        int j = threadIdx.x;
        bool done = (j >= nb);
        while (!done) {
            unsigned v = __hip_atomic_load((unsigned*)(arr + (size_t)j * 32),
                                           __ATOMIC_ACQUIRE,
                                           __HIP_MEMORY_SCOPE_AGENT);
            done = (v >= p);
            if (!done) __builtin_amdgcn_s_sleep(4);
        }
    }
    __syncthreads();
}

// ---------------------------------------------------------------- chain kernel
__global__ void __launch_bounds__(256) chain_kernel(
    float* __restrict__ hA, float* __restrict__ hB,
    float* __restrict__ zb, float* __restrict__ skipv, float* __restrict__ e1v,
    unsigned* __restrict__ arrive_base,
    const float* __restrict__ filt_w, const float* __restrict__ filt_b,
    const float* __restrict__ gate_w, const float* __restrict__ gate_b,
    const float* __restrict__ res_w,  const float* __restrict__ res_b,
    const float* __restrict__ skip_w, const float* __restrict__ skip_b,
    const float* __restrict__ e1w, const float* __restrict__ e1b,
    const float* __restrict__ e2w, const float* __restrict__ e2b,
    float* __restrict__ out, int NB, int NBSH)
{
    const int tid = threadIdx.x;
    const int grp = blockIdx.x >> NBSH;      // batch index
    const int g   = blockIdx.x & (NB - 1);   // block within group
    const int b   = grp;

    volatile unsigned* arr = arrive_base + (size_t)grp * MAXNB * 32;
    unsigned p = 0;

    union __align__(16) Sh {
        struct {
            float hc[RC][68], hp[RC][68], zt[RC][68];
            float wf0[RC][33], wf1[RC][33], wg0[RC][33], wg1[RC][33], wrs[RC][33];
            float bfs[RC], bgs[RC], brs[RC];
        } L;                                              // 47.6 KB
        struct { float z[160][32]; float w[5][16][32]; } E1;   // 30 KB
        struct { float v[256][32]; float w[16][256]; } E2;     // 48 KB
    };
    __shared__ Sh sh;

    // ---------------- 30-layer chain ----------------
    int S = 3069;
    for (int i = 0; i < NLAYERS; ++i) {
        int d = 1 << (i % 10);
        S -= d;
        int A1 = 4064 - S;
        int nT = (4096 - A1 + 63) >> 6;
        const float* hin = (i & 1) ? hB : hA;
        float*       hout = (i & 1) ? hA : hB;

        if (g < nT) {
            const float* fw = filt_w + (size_t)i * RC * RC * 2;
            const float* gw = gate_w + (size_t)i * RC * RC * 2;
            const float* rw = res_w  + (size_t)i * RC * RC;
            for (int idx = tid; idx < RC * RC; idx += 256) {
                int c = idx >> 5, c2 = idx & 31;
                sh.L.wf0[c][c2] = fw[idx * 2];  sh.L.wf1[c][c2] = fw[idx * 2 + 1];
                sh.L.wg0[c][c2] = gw[idx * 2];  sh.L.wg1[c][c2] = gw[idx * 2 + 1];
                sh.L.wrs[c][c2] = rw[idx];
            }
            if (tid < RC) {
                sh.L.bfs[tid] = filt_b[i * RC + tid];
                sh.L.bgs[tid] = gate_b[i * RC + tid];
                sh.L.brs[tid] = res_b[i * RC + tid];
            }

            for (int tile = g; tile < nT; tile += NB) {
                int t_lo = 4032 - (tile << 6);
                __syncthreads();
                for (int idx = tid; idx < RC * 64; idx += 256) {
                    int c2 = idx >> 6, tx = idx & 63;
                    const float* row = hin + ((size_t)b * RC + c2) * TLEN;
                    int t = t_lo + tx;
                    sh.L.hc[c2][tx] = row[t];
                    sh.L.hp[c2][tx] = row[t - d];
                }
                __syncthreads();

                int c  = tid & 31;
                int tl = tid >> 5;
                float fa[8], ga[8];
                float bfv = sh.L.bfs[c], bgv = sh.L.bgs[c];
                #pragma unroll
                for (int k = 0; k < 8; ++k) { fa[k] = bfv; ga[k] = bgv; }

                #pragma unroll 4
                for (int c2 = 0; c2 < RC; ++c2) {
                    float w0f = sh.L.wf0[c][c2], w1f = sh.L.wf1[c][c2];
                    float w0g = sh.L.wg0[c][c2], w1g = sh.L.wg1[c][c2];
                    const float4* hcr = (const float4*)&sh.L.hc[c2][0];
                    const float4* hpr = (const float4*)&sh.L.hp[c2][0];
                    float4 c0 = hcr[tl * 2], c1 = hcr[tl * 2 + 1];
                    float4 p0 = hpr[tl * 2], p1 = hpr[tl * 2 + 1];
                    float hcv[8] = {c0.x, c0.y, c0.z, c0.w, c1.x, c1.y, c1.z, c1.w};
                    float hpv[8] = {p0.x, p0.y, p0.z, p0.w, p1.x, p1.y, p1.z, p1.w};
                    #pragma unroll
                    for (int k = 0; k < 8; ++k) {
                        fa[k] += w0f * hpv[k] + w1f * hcv[k];
                        ga[k] += w0g * hpv[k] + w1g * hcv[k];
                    }
                }
                #pragma unroll
                for (int k = 0; k < 8; ++k) {
                    float e2 = __expf(2.0f * fa[k]);
                    float th = 1.0f - 2.0f / (e2 + 1.0f);
                    float sg = 1.0f / (1.0f + __expf(-ga[k]));
                    sh.L.zt[c][tl * 8 + k] = th * sg;
                }
                __syncthreads();

                float ra[8];
                float brv = sh.L.brs[c];
                #pragma unroll
                for (int k = 0; k < 8; ++k) ra[k] = brv;
                #pragma unroll 4
                for (int c2 = 0; c2 < RC; ++c2) {
                    float wv = sh.L.wrs[c][c2];
                    const float4* zr = (const float4*)&sh.L.zt[c2][0];
                    float4 z0 = zr[tl * 2], z1 = zr[tl * 2 + 1];
                    float zv[8] = {z0.x, z0.y, z0.z, z0.w, z1.x, z1.y, z1.z, z1.w};
                    #pragma unroll
                    for (int k = 0; k < 8; ++k) ra[k] += wv * zv[k];
                }
                #pragma unroll
                for (int k = 0; k < 8; ++k) {
                    int tx = tl * 8 + k;
                    sh.L.hp[c][tx] = sh.L.hc[c][tx] + ra[k];
                }
                __syncthreads();

                for (int idx = tid; idx < RC * 64; idx += 256) {
                    int c2 = idx >> 6, tx = idx & 63;
                    int t = t_lo + tx;
                    if (t >= A1) hout[((size_t)b * RC + c2) * TLEN + t] = sh.L.hp[c2][tx];
                }
                if (tile == 0) {   // z tail, K-major: zb[layer*32+c][n], n=b*32+tt
                    for (int idx = tid; idx < RC * OUT_T; idx += 256) {
                        int c2 = idx >> 5, tt = idx & 31;
                        zb[((size_t)i * RC + c2) * NCOL + b * OUT_T + tt] =
                            sh.L.zt[c2][32 + tt];
                    }
                }
            }
        }
        ++p;
        grp_barrier(arr, g, NB, p);
    }

    // ---------------- end stage, group-local (columns b*32..b*32+31) ----------
    const int n   = tid & 31;
    const int s8  = tid >> 5;            // 0..7
    const int R   = 256 >> NBSH;         // rows per block (8 or 16)
    const int RQ  = R >> 3;              // 1 or 2
    const int sc0 = g * R;

    // G1: skip[sc][n] = relu( sum_{l,k} skip_w[l][sc][k]*z[l*32+k][n] + sum_l skip_b[l][sc] )
    {
        float a[2] = {0.f, 0.f};
        for (int ch = 0; ch < 6; ++ch) {          // 5 layers per chunk
            __syncthreads();
            for (int idx = tid; idx < 160 * 8; idx += 256) {
                int kk = idx >> 3, k4 = idx & 7;
                ((float4*)&sh.E1.z[kk][0])[k4] =
                    ((const float4*)zb)[(size_t)(ch * 160 + kk) * (NCOL / 4) + b * 8 + k4];
            }
            for (int idx = tid; idx < 5 * R * 8; idx += 256) {
                int l = idx / (R * 8); int rem = idx - l * R * 8;
                int r = rem >> 3, k4 = rem & 7;
                ((float4*)&sh.E1.w[l][r][0])[k4] =
                    ((const float4*)skip_w)[((size_t)(ch * 5 + l) * SKIPC + sc0 + r) * 8 + k4];
            }
            __syncthreads();
            #pragma unroll
            for (int l = 0; l < 5; ++l) {
                #pragma unroll 8
                for (int k = 0; k < RC; ++k) {
                    float zv = sh.E1.z[l * 32 + k][n];
                    for (int q = 0; q < RQ; ++q)
                        a[q] += sh.E1.w[l][s8 + 8 * q][k] * zv;
                }
            }
        }
        for (int q = 0; q < RQ; ++q) {
            int sc = sc0 + s8 + 8 * q;
            float sb = 0.f;
            for (int l = 0; l < NLAYERS; ++l) sb += skip_b[l * SKIPC + sc];
            skipv[((size_t)b * SKIPC + sc) * 32 + n] = fmaxf(a[q] + sb, 0.f);
        }
    }
    ++p; grp_barrier(arr, g, NB, p);

    // G2: e1 = relu(e1w @ skipv + e1b)
    {
        __syncthreads();
        for (int idx = tid; idx < 256 * 8; idx += 256) {
            int r = idx >> 3, k4 = idx & 7;
            ((float4*)&sh.E2.v[r][0])[k4] =
                ((const float4*)skipv)[((size_t)b * SKIPC + r) * 8 + k4];
        }
        for (int idx = tid; idx < R * 64; idx += 256) {
            int r = idx >> 6, k4 = idx & 63;
            ((float4*)&sh.E2.w[r][0])[k4] =
                ((const float4*)e1w)[(size_t)(sc0 + r) * 64 + k4];
        }
        __syncthreads();
        float a[2];
        for (int q = 0; q < RQ; ++q) a[q] = e1b[sc0 + s8 + 8 * q];
        #pragma unroll 8
        for (int k4 = 0; k4 < 64; ++k4) {
            float v0 = sh.E2.v[k4 * 4 + 0][n], v1 = sh.E2.v[k4 * 4 + 1][n];
            float v2 = sh.E2.v[k4 * 4 + 2][n], v3 = sh.E2.v[k4 * 4 + 3][n];
            for (int q = 0; q < RQ; ++q) {
                float4 w0 = ((const float4*)&sh.E2.w[s8 + 8 * q][0])[k4];
                a[q] += w0.x * v0 + w0.y * v1 + w0.z * v2 + w0.w * v3;
            }
        }
        for (int q = 0; q < RQ; ++q)
            e1v[((size_t)b * ENDC + sc0 + s8 + 8 * q) * 32 + n] = fmaxf(a[q], 0.f);
    }
    ++p; grp_barrier(arr, g, NB, p);

    // G3: out[b*32+n][sc] = e2w @ e1v + e2b
    {
        __syncthreads();
        for (int idx = tid; idx < 256 * 8; idx += 256) {
            int r = idx >> 3, k4 = idx & 7;
            ((float4*)&sh.E2.v[r][0])[k4] =
                ((const float4*)e1v)[((size_t)b * ENDC + r) * 8 + k4];
        }
        for (int idx = tid; idx < R * 64; idx += 256) {
            int r = idx >> 6, k4 = idx & 63;
            ((float4*)&sh.E2.w[r][0])[k4] =
                ((const float4*)e2w)[(size_t)(sc0 + r) * 64 + k4];
        }
        __syncthreads();
        float a[2];
        for (int q = 0; q < RQ; ++q) a[q] = e2b[sc0 + s8 + 8 * q];
        #pragma unroll 8
        for (int k4 = 0; k4 < 64; ++k4) {
            float v0 = sh.E2.v[k4 * 4 + 0][n], v1 = sh.E2.v[k4 * 4 + 1][n];
            float v2 = sh.E2.v[k4 * 4 + 2][n], v3 = sh.E2.v[k4 * 4 + 3][n];
            for (int q = 0; q < RQ; ++q) {
                float4 w0 = ((const float4*)&sh.E2.w[s8 + 8 * q][0])[k4];
                a[q] += w0.x * v0 + w0.y * v1 + w0.z * v2 + w0.w * v3;
            }
        }
        for (int q = 0; q < RQ; ++q)
            out[(size_t)(b * OUT_T + n) * CLASSES + sc0 + s8 + 8 * q] = a[q];
    }
}

// ---------------------------------------------------------------- launch
extern "C" void kernel_launch(void* const* d_in, const int* in_sizes, int n_in,
                              void* d_out, int out_size, void* d_ws, size_t ws_size,
                              hipStream_t stream)
{
    const float* x        = (const float*)d_in[0];
    const float* causal_w = (const float*)d_in[1];
    const float* causal_b = (const float*)d_in[2];
    const float* filt_w   = (const float*)d_in[3];
    const float* filt_b   = (const float*)d_in[4];
    const float* gate_w   = (const float*)d_in[5];
    const float* gate_b   = (const float*)d_in[6];
    const float* res_w    = (const float*)d_in[7];
    const float* res_b    = (const float*)d_in[8];
    const float* skip_w   = (const float*)d_in[9];
    const float* skip_b   = (const float*)d_in[10];
    const float* e1w      = (const float*)d_in[11];
    const float* e1b      = (const float*)d_in[12];
    const float* e2w      = (const float*)d_in[13];
    const float* e2b      = (const float*)d_in[14];
    float* outp           = (float*)d_out;

    const size_t HSZ = (size_t)BATCH * RC * TLEN;      // 2,097,152 floats
    float* hA    = (float*)d_ws;
    float* hB    = hA + HSZ;
    float* zb    = hB + HSZ;                           // 960 * 512
    float* skipv = zb + (size_t)NLAYERS * RC * NCOL;
    float* e1v   = skipv + (size_t)SKIPC * NCOL;
    unsigned* arrive = (unsigned*)(e1v + (size_t)ENDC * NCOL);  // 16*32*32 u32

    hipMemsetAsync(arrive, 0, (size_t)BATCH * MAXNB * 32 * sizeof(unsigned),
                   stream);

    causal_kernel<<<dim3(BATCH * 97), dim3(256), 0, stream>>>(x, causal_w, causal_b, hA);

    int NB = 32, NBSH = 5;   // 512 blocks = 2/CU (48KB LDS, 96 VGPR -> fits)
    void* args[] = {
        (void*)&hA, (void*)&hB, (void*)&zb, (void*)&skipv, (void*)&e1v,
        (void*)&arrive,
        (void*)&filt_w, (void*)&filt_b, (void*)&gate_w, (void*)&gate_b,
        (void*)&res_w, (void*)&res_b, (void*)&skip_w, (void*)&skip_b,
        (void*)&e1w, (void*)&e1b, (void*)&e2w, (void*)&e2b, (void*)&outp,
        (void*)&NB, (void*)&NBSH
    };
    hipError_t err = hipLaunchCooperativeKernel((const void*)chain_kernel,
                                                dim3(BATCH * NB), dim3(256),
                                                args, 0, stream);
    if (err != hipSuccess) {
        // fall back to the R4-proven 256-block grid (1 block/CU guaranteed)
        NB = 16; NBSH = 4;
        hipLaunchCooperativeKernel((const void*)chain_kernel,
                                   dim3(BATCH * NB), dim3(256),
                                   args, 0, stream);
    }
}